// Round 5
// baseline (248.247 us; speedup 1.0000x reference)
//
#include <hip/hip_runtime.h>
#include <hip/hip_bf16.h>

// ---------------------------------------------------------------------------
// NHRepNet fused forward, Round 5.
//
// R5 changes vs R4 (main 138us, MfmaUtil 26%, VALU 43%, LDS pipe ~55% w/
// 12.8M bank conflicts = 8-way on b128 column reads):
//  - XOR-swizzled activation layout: row r, 16B-granule g stored at g^(r&7).
//    B-read bank group = (kk*4+quad)^(l15&7) -> 2 lanes/group (free) instead
//    of 8-way. LDA=256 (512B rows), no pad needed.
//  - Ping-pong act buffers: 1 barrier/layer (was 2). Layer-N reads of src
//    precede the barrier; layer-N+1 writes to that buffer follow it.
//  - Keep R4 structure: 512-thr blocks, wave owns 32 ch, acc[2][2]=16 AGPR,
//    <=64 regs -> 8 waves/SIMD; scale folding (t2-domain, weights prescaled).
// ---------------------------------------------------------------------------

using bf16x8 = __attribute__((ext_vector_type(8))) __bf16;
using f32x4  = __attribute__((ext_vector_type(4))) float;

#define OFFW0 0
#define OFFW1 8192
#define OFFW2 73728
#define OFFW3 139264
#define OFFW4 204800
#define OFFW5 270336
#define OFFW6 335872
#define OFFW7 401408
#define WSB_BYTE_OFF 811008   // fp32 bias region
#define OFFB7 1792            // L0..L6 at l*256; L7 at 1792 (16 floats, padded)

#define SCALE_T2 144.26950408889634f      // 100*log2(e)
#define INV_SQRT2 0.70710678118654752f
#define LN2_100 0.0069314718055994531f    // ln2/100

__device__ __forceinline__ float fast_exp2(float x) {
#if __has_builtin(__builtin_amdgcn_exp2f)
    return __builtin_amdgcn_exp2f(x);
#else
    return exp2f(x);
#endif
}
__device__ __forceinline__ float fast_log2(float x) {
#if __has_builtin(__builtin_amdgcn_logf)
    return __builtin_amdgcn_logf(x);
#else
    return log2f(x);
#endif
}

// a2 = max(t2,0) + log2(1 + 2^-|t2|)
__device__ __forceinline__ float softplus_t2(float t2) {
    float e = fast_exp2(-fabsf(t2));
    float l = fast_log2(1.0f + e);
    return fmaxf(t2, 0.0f) + l;
}

__device__ __forceinline__ unsigned short bf16_rne(float f) {
    unsigned int u = __float_as_uint(f);
    unsigned int r = u + 0x7FFFu + ((u >> 16) & 1u);
    return (unsigned short)(r >> 16);
}

// Swizzled byte address into a [32 pts][512 B] act buffer:
// granule (16B) g of row pt lives at g ^ (pt & 7).
__device__ __forceinline__ int sw_addr(int pt, int byte_col) {
    return pt * 512 + ((((byte_col >> 4) ^ (pt & 7)) << 4) | (byte_col & 15));
}

// One 256-out layer, src -> dst (ping-pong). Wave w (of 8) owns channels
// [w*32, w*32+32). MODE 0: softplus. MODE 1: layer-3 (softplus; splice raw x
// into ch 253..255 — scales folded into W4 rows).
template <int KK, int MODE>
__device__ __forceinline__ void layer_mm(
    const unsigned short* __restrict__ wfrag,
    const float* __restrict__ bias,
    const unsigned short* src, unsigned short* dst,
    const float* xst, int wave, int lane)
{
    const int quad = lane >> 4;
    const int l15  = lane & 15;
    const int sw   = l15 & 7;

    f32x4 acc[2][2];
#pragma unroll
    for (int i = 0; i < 2; ++i) {
        const int chb = (wave * 2 + i) * 16 + quad * 4;
        const float4 b4 = *(const float4*)(bias + chb);
#pragma unroll
        for (int nt = 0; nt < 2; ++nt)
            acc[i][nt] = f32x4{b4.x, b4.y, b4.z, b4.w};
    }

#pragma unroll
    for (int kk = 0; kk < KK; ++kk) {
        bf16x8 bfr[2];
#pragma unroll
        for (int nt = 0; nt < 2; ++nt)
            bfr[nt] = *(const bf16x8*)((const char*)src +
                        (nt * 16 + l15) * 512 + (((kk * 4 + quad) ^ sw) << 4));
#pragma unroll
        for (int i = 0; i < 2; ++i) {
            const int mt = wave * 2 + i;
            bf16x8 afr = *(const bf16x8*)(wfrag + ((mt * KK + kk) * 64 + lane) * 8);
#pragma unroll
            for (int nt = 0; nt < 2; ++nt)
                acc[i][nt] = __builtin_amdgcn_mfma_f32_16x16x32_bf16(afr, bfr[nt], acc[i][nt], 0, 0, 0);
        }
    }

    // epilogue straight into dst (different buffer: no barrier needed first)
#pragma unroll
    for (int i = 0; i < 2; ++i) {
        const int chb = (wave * 2 + i) * 16 + quad * 4;
#pragma unroll
        for (int nt = 0; nt < 2; ++nt) {
            const int pt = nt * 16 + l15;
            float vv[4];
#pragma unroll
            for (int r = 0; r < 4; ++r) {
                float s = softplus_t2(acc[i][nt][r]);
                if (MODE == 1) {
                    const int ch = chb + r;
                    if (ch >= 253)  // splice raw x (W4 rows absorb scales)
                        s = xst[pt * 4 + (ch - 253)];
                }
                vv[r] = s;
            }
            __hip_bfloat162 p01 = __float22bfloat162_rn(float2{vv[0], vv[1]});
            __hip_bfloat162 p23 = __float22bfloat162_rn(float2{vv[2], vv[3]});
            uint2 pk;
            pk.x = *(unsigned int*)&p01;
            pk.y = *(unsigned int*)&p23;
            *(uint2*)((char*)dst + sw_addr(pt, chb * 2)) = pk;
        }
    }

    __syncthreads();   // dst visible before next layer reads it
}

__global__ __launch_bounds__(512, 8)
void nhrep_main(const float* __restrict__ x, float* __restrict__ out,
                const unsigned short* __restrict__ wsW,
                const float* __restrict__ wsB, int npts)
{
    __shared__ unsigned short actA[32 * 256];  // 16384 B
    __shared__ unsigned short actB[32 * 256];  // 16384 B
    __shared__ float xst[32 * 4];              // 512 B -> 33280 B total
    const int tid  = threadIdx.x;
    const int wave = tid >> 6, lane = tid & 63;
    const int quad = lane >> 4, l15 = lane & 15;
    const int base_pt = blockIdx.x * 32;

    // stage x into actA channels 0..2 (swizzled), zero-pad to 32
    for (int i = tid; i < 32 * 32; i += 512) {
        const int pt = i >> 5, ch = i & 31;
        const int ptg = base_pt + pt;
        float v = 0.0f;
        if (ch < 3 && ptg < npts) v = x[ptg * 3 + ch];
        *(unsigned short*)((char*)actA + sw_addr(pt, ch * 2)) = bf16_rne(v);
        if (ch < 4) xst[pt * 4 + ch] = (ch < 3) ? v : 0.0f;
    }
    __syncthreads();

    layer_mm<1, 0>(wsW + OFFW0, wsB + 0 * 256, actA, actB, xst, wave, lane);
    layer_mm<8, 0>(wsW + OFFW1, wsB + 1 * 256, actB, actA, xst, wave, lane);
    layer_mm<8, 0>(wsW + OFFW2, wsB + 2 * 256, actA, actB, xst, wave, lane);
    layer_mm<8, 1>(wsW + OFFW3, wsB + 3 * 256, actB, actA, xst, wave, lane);
    layer_mm<8, 0>(wsW + OFFW4, wsB + 4 * 256, actA, actB, xst, wave, lane);
    layer_mm<8, 0>(wsW + OFFW5, wsB + 5 * 256, actB, actA, xst, wave, lane);
    layer_mm<8, 0>(wsW + OFFW6, wsB + 6 * 256, actA, actB, xst, wave, lane);

    // layer 7: 256 -> 8 (W7 pre-scaled ln2/100, b7 raw). Waves 0,1: 16 pts each.
    if (wave < 2) {
        const float4 b4 = *(const float4*)(wsB + OFFB7 + quad * 4);  // quads>=2: zeros
        f32x4 acc = f32x4{b4.x, b4.y, b4.z, b4.w};
        const unsigned short* w7 = wsW + OFFW7;
        const int sw = l15 & 7;
#pragma unroll
        for (int kk = 0; kk < 8; ++kk) {
            bf16x8 bfr = *(const bf16x8*)((const char*)actB +
                           (wave * 16 + l15) * 512 + (((kk * 4 + quad) ^ sw) << 4));
            bf16x8 afr = *(const bf16x8*)(w7 + (kk * 64 + lane) * 8);
            acc = __builtin_amdgcn_mfma_f32_16x16x32_bf16(afr, bfr, acc, 0, 0, 0);
        }
        // quad0 lanes hold ch0-3, quad1 ch4-7 for pt = wave*16+l15
        float u0 = __shfl(acc[0], l15 + 16);
        float u1 = __shfl(acc[1], l15 + 16);
        float u2 = __shfl(acc[2], l15 + 16);
        float u3 = __shfl(acc[3], l15 + 16);
        if (quad == 0) {
            const int ptg = base_pt + wave * 16 + l15;
            if (ptg < npts) {
                const float v0 = acc[0], v1 = acc[1], v2 = acc[2], v3 = acc[3];
                const float v4 = u0, v5 = u1, v6 = u2, v7 = u3;
                const float m23   = fminf(v2, v3);
                const float m67   = fmaxf(v6, v7);
                const float m4567 = fminf(fminf(v4, v5), m67);
                const float h     = fmaxf(fmaxf(v0, v1), fmaxf(m23, m4567));
                float* o = out + (long)ptg * 9;
                o[0] = h;
                o[1] = v0; o[2] = v1; o[3] = v2; o[4] = v3;
                o[5] = v4; o[6] = v5; o[7] = v6; o[8] = v7;
            }
        }
    }
}

// ---------------------------------------------------------------------------
// Fused prepack with scale folding. Frag (mt,kk,lane,j) =
// scale(l,k) * W^T[mt*16+(lane&15)][k = kk*32+(lane>>4)*8+j], zero-padded.
// ---------------------------------------------------------------------------
struct PackArgs {
    const float* W[8];
    const float* b[8];
};

#define TOTAL_FRAGS 50688
#define TOTAL_BIAS  1808

__global__ void prepack_all(PackArgs args, unsigned short* __restrict__ dstW,
                            float* __restrict__ dstB)
{
    const int t = blockIdx.x * blockDim.x + threadIdx.x;
    const int FB[9]  = {0, 1024, 9216, 17408, 25600, 33792, 41984, 50176, 50688};
    const int KKs[8] = {1, 8, 8, 8, 8, 8, 8, 8};
    const int ind[8] = {3, 256, 256, 256, 256, 256, 256, 256};
    const int outd[8]= {256, 256, 256, 253, 256, 256, 256, 8};

    if (t < TOTAL_FRAGS) {
        int l = 0;
        while (t >= FB[l + 1]) ++l;
        const int f    = t - FB[l];
        const int lane = f & 63;
        const int kk   = (f >> 6) % KKs[l];
        const int mt   = f / (64 * KKs[l]);
        const int o    = mt * 16 + (lane & 15);
        const int kb   = kk * 32 + (lane >> 4) * 8;
        const float* W = args.W[l];
        const int in_d = ind[l], out_d = outd[l];

        unsigned short v[8];
#pragma unroll
        for (int j = 0; j < 8; ++j) {
            const int k = kb + j;
            float w = 0.0f;
            if (k < in_d && o < out_d) {
                float sc = 1.0f;
                if (l == 0) sc = SCALE_T2;
                else if (l == 4) sc = (k < 253) ? INV_SQRT2 : (SCALE_T2 * INV_SQRT2);
                else if (l == 7) sc = LN2_100;
                w = W[k * out_d + o] * sc;
            }
            unsigned int u = __float_as_uint(w);
            v[j] = (unsigned short)((u + 0x7FFFu + ((u >> 16) & 1u)) >> 16);
        }
        uint4 p;
        p.x = (unsigned int)v[0] | ((unsigned int)v[1] << 16);
        p.y = (unsigned int)v[2] | ((unsigned int)v[3] << 16);
        p.z = (unsigned int)v[4] | ((unsigned int)v[5] << 16);
        p.w = (unsigned int)v[6] | ((unsigned int)v[7] << 16);
        *(uint4*)(dstW + (long)t * 8) = p;
    } else if (t < TOTAL_FRAGS + TOTAL_BIAS) {
        const int u = t - TOTAL_FRAGS;
        const int l = (u < 1792) ? (u >> 8) : 7;
        const int idx = (l < 7) ? (u & 255) : (u - 1792);
        const float sc = (l < 7) ? SCALE_T2 : 1.0f;   // b7 stays in output units
        dstB[u] = (idx < outd[l]) ? args.b[l][idx] * sc : 0.0f;
    }
}

extern "C" void kernel_launch(void* const* d_in, const int* in_sizes, int n_in,
                              void* d_out, int out_size, void* d_ws, size_t ws_size,
                              hipStream_t stream)
{
    const float* x = (const float*)d_in[0];
    unsigned short* wsW = (unsigned short*)d_ws;
    float* wsB = (float*)((char*)d_ws + WSB_BYTE_OFF);

    PackArgs pa;
    for (int l = 0; l < 8; ++l) {
        pa.W[l] = (const float*)d_in[1 + 2 * l];
        pa.b[l] = (const float*)d_in[2 + 2 * l];
    }
    const int ptot = TOTAL_FRAGS + TOTAL_BIAS;
    prepack_all<<<(ptot + 255) / 256, 256, 0, stream>>>(pa, wsW, wsB);

    const int npts = in_sizes[0] / 3;            // 100000
    const int nblk = (npts + 31) / 32;           // 3125 exactly
    nhrep_main<<<nblk, 512, 0, stream>>>(x, (float*)d_out, wsW, wsB, npts);
}